// Round 1
// baseline (561.921 us; speedup 1.0000x reference)
//
#include <hip/hip_runtime.h>
#include <math.h>

#define T_STEPS 1440
#define TILE 16
#define NTILES (T_STEPS / TILE)   // 90

__device__ __forceinline__ float sigf(float x) { return 1.0f / (1.0f + expf(-x)); }

__device__ __forceinline__ void step_tile(const float4* buf, float& t_in, float& t_env,
                                          float a1, float b1, float b2,
                                          float ksi, float kse, float kh,
                                          float* o) {
#pragma unroll
    for (int j = 0; j < TILE; ++j) {
        float4 x = buf[j];
        // x = (t_in_seq, t_out, hvac_u, solar) -- x.x unused except at t=0
        float nti = fmaf(a1, t_env - t_in, t_in);
        nti = fmaf(ksi, x.w, nti);
        nti = fmaf(kh, x.z, nti);
        float nte = fmaf(b1, t_in - t_env, t_env);
        nte = fmaf(b2, x.y - t_env, nte);
        nte = fmaf(kse, x.w, nte);
        t_in = nti;
        t_env = nte;
        o[j] = nti;
    }
}

__global__ __launch_bounds__(64, 1) void rc_scan_kernel(
    const float4* __restrict__ in,
    const float* __restrict__ p_ri, const float* __restrict__ p_re,
    const float* __restrict__ p_ci, const float* __restrict__ p_ce,
    const float* __restrict__ p_ai, const float* __restrict__ p_ae,
    const float* __restrict__ p_hg,
    float4* __restrict__ out)
{
    const int b = blockIdx.x * blockDim.x + threadIdx.x;

    // sigmoid-bounded params (uniform across all threads; scalar-cached)
    const float Ri = 1.0e-4f + (0.2f - 1.0e-4f) * sigf(p_ri[0]);
    const float Re = 1.0e-4f + (0.2f - 1.0e-4f) * sigf(p_re[0]);
    const float Ci = 1.0e5f + (1.0e8f - 1.0e5f) * sigf(p_ci[0]);
    const float Ce = 1.0e5f + (1.0e8f - 1.0e5f) * sigf(p_ce[0]);
    const float Ai = 0.2f * sigf(p_ai[0]);
    const float Ae = 0.2f * sigf(p_ae[0]);
    const float hg = 1.0f + (20000.0f - 1.0f) * sigf(p_hg[0]);

    const float DT = 300.0f;
    const float a1  = DT / (Ri * Ci);
    const float b1  = DT / (Ri * Ce);
    const float b2  = DT / (Re * Ce);
    const float ksi = DT * Ai / Ci;
    const float kse = DT * Ae / Ce;
    const float kh  = -DT * hg / Ci;   // MODE_COOL => cooling_sign = -1

    const float4* p = in + (size_t)b * T_STEPS;        // one float4 per timestep
    float4* ob = out + (size_t)b * (T_STEPS / 4);      // 4 preds per float4

    // ping-pong register prefetch buffers: 16 dwordx4 loads in flight while
    // computing the other tile (16 KB/wave in flight at steady state)
    float4 bufA[TILE], bufB[TILE];
#pragma unroll
    for (int j = 0; j < TILE; ++j) bufA[j] = p[j];
#pragma unroll
    for (int j = 0; j < TILE; ++j) bufB[j] = p[TILE + j];

    float t_in  = bufA[0].x;
    float t_env = 0.5f * (bufA[0].x + bufA[0].y);

    float oA[TILE], oB[TILE];

    for (int tile = 0; tile < NTILES; tile += 2) {
        // ---- compute tile (A) ----
        step_tile(bufA, t_in, t_env, a1, b1, b2, ksi, kse, kh, oA);
        // refill A with tile+2 (uniform branch)
        if (tile + 2 < NTILES) {
            const float4* np_ = p + (size_t)(tile + 2) * TILE;
#pragma unroll
            for (int j = 0; j < TILE; ++j) bufA[j] = np_[j];
        }
        {
            float4* dst = ob + (size_t)tile * (TILE / 4);
            dst[0] = make_float4(oA[0],  oA[1],  oA[2],  oA[3]);
            dst[1] = make_float4(oA[4],  oA[5],  oA[6],  oA[7]);
            dst[2] = make_float4(oA[8],  oA[9],  oA[10], oA[11]);
            dst[3] = make_float4(oA[12], oA[13], oA[14], oA[15]);
        }
        // ---- compute tile+1 (B) ----
        step_tile(bufB, t_in, t_env, a1, b1, b2, ksi, kse, kh, oB);
        if (tile + 3 < NTILES) {
            const float4* np_ = p + (size_t)(tile + 3) * TILE;
#pragma unroll
            for (int j = 0; j < TILE; ++j) bufB[j] = np_[j];
        }
        {
            float4* dst = ob + (size_t)(tile + 1) * (TILE / 4);
            dst[0] = make_float4(oB[0],  oB[1],  oB[2],  oB[3]);
            dst[1] = make_float4(oB[4],  oB[5],  oB[6],  oB[7]);
            dst[2] = make_float4(oB[8],  oB[9],  oB[10], oB[11]);
            dst[3] = make_float4(oB[12], oB[13], oB[14], oB[15]);
        }
    }
}

extern "C" void kernel_launch(void* const* d_in, const int* in_sizes, int n_in,
                              void* d_out, int out_size, void* d_ws, size_t ws_size,
                              hipStream_t stream) {
    const float4* in = (const float4*)d_in[0];
    const float* p_ri = (const float*)d_in[1];
    const float* p_re = (const float*)d_in[2];
    const float* p_ci = (const float*)d_in[3];
    const float* p_ce = (const float*)d_in[4];
    const float* p_ai = (const float*)d_in[5];
    const float* p_ae = (const float*)d_in[6];
    const float* p_hg = (const float*)d_in[7];
    float4* out = (float4*)d_out;

    const int B = in_sizes[0] / (T_STEPS * 4);   // 16384
    const int block = 64;
    const int grid = B / block;                  // 256 blocks -> 1 per CU

    rc_scan_kernel<<<grid, block, 0, stream>>>(in, p_ri, p_re, p_ci, p_ce,
                                               p_ai, p_ae, p_hg, out);
}